// Round 2
// baseline (1947.843 us; speedup 1.0000x reference)
//
#include <hip/hip_runtime.h>

#define TT 512
#define BB 64
#define EE 300
#define HH 150
#define G3 450
#define AT 75

__device__ __forceinline__ float fast_rcp(float x) { return __builtin_amdgcn_rcpf(x); }
__device__ __forceinline__ float sigmoid_f(float x) { return fast_rcp(1.f + __expf(-x)); }
__device__ __forceinline__ float tanh_f(float x) {
  float e = __expf(2.f * x);          // inf for large x -> result 1; 0 for very negative -> -1
  return 1.f - 2.f * fast_rcp(e + 1.f);
}
__device__ __forceinline__ float bcast_lane(float v, int k) {
  return __int_as_float(__builtin_amdgcn_readlane(__float_as_int(v), k));
}

// ---------------- transpose prep ----------------
__global__ void k_prep(const float* __restrict__ Wih0, const float* __restrict__ Whh0,
                       const float* __restrict__ Wih1, const float* __restrict__ Whh1,
                       const float* __restrict__ W1,   const float* __restrict__ fc1w,
                       float* __restrict__ Wih0T, float* __restrict__ Whh0T,
                       float* __restrict__ Wih1T, float* __restrict__ Whh1T,
                       float* __restrict__ W1T,   float* __restrict__ fc1T) {
  int tid = blockIdx.x * blockDim.x + threadIdx.x;
  int nt = gridDim.x * blockDim.x;
  for (int i = tid; i < G3 * EE; i += nt) { int r = i / EE, c = i - r * EE; Wih0T[c * G3 + r] = Wih0[i]; }
  for (int i = tid; i < G3 * HH; i += nt) { int r = i / HH, c = i - r * HH; Whh0T[c * G3 + r] = Whh0[i]; }
  for (int i = tid; i < G3 * HH; i += nt) { int r = i / HH, c = i - r * HH; Wih1T[c * G3 + r] = Wih1[i]; }
  for (int i = tid; i < G3 * HH; i += nt) { int r = i / HH, c = i - r * HH; Whh1T[c * G3 + r] = Whh1[i]; }
  for (int i = tid; i < AT * HH; i += nt) { int r = i / HH, c = i - r * HH; W1T[c * AT + r] = W1[i]; }
  for (int i = tid; i < HH * HH; i += nt) { int r = i / HH, c = i - r * HH; fc1T[c * HH + r] = fc1w[i]; }
}

// ---------------- layer-0 input projection: gather + [32768,300]@[300,450] ----------------
__global__ __launch_bounds__(512) void k_xw0(const int* __restrict__ texts,
                                             const float* __restrict__ emb,
                                             const float* __restrict__ WihT,
                                             const float* __restrict__ bih,
                                             float* __restrict__ xw) {
  __shared__ __align__(16) float a_lds[32 * EE];
  const int row0 = blockIdx.x * 32;
  const int tid = threadIdx.x;
  for (int p = tid; p < 32 * EE; p += 512) {
    int r = p / EE, e = p - r * EE;
    int vrow = texts[row0 + r];
    a_lds[p] = emb[(size_t)vrow * EE + e];
  }
  __syncthreads();
  const int g = tid;
  if (g < G3) {
    float acc[32];
#pragma unroll
    for (int r = 0; r < 32; ++r) acc[r] = 0.f;
    const float bias = bih[g];
    for (int k = 0; k < EE; k += 4) {
      float w0 = WihT[(k + 0) * G3 + g];
      float w1 = WihT[(k + 1) * G3 + g];
      float w2v = WihT[(k + 2) * G3 + g];
      float w3 = WihT[(k + 3) * G3 + g];
#pragma unroll
      for (int r = 0; r < 32; ++r) {
        const float4 av = *reinterpret_cast<const float4*>(&a_lds[r * EE + k]);
        acc[r] = fmaf(av.x, w0, acc[r]);
        acc[r] = fmaf(av.y, w1, acc[r]);
        acc[r] = fmaf(av.z, w2v, acc[r]);
        acc[r] = fmaf(av.w, w3, acc[r]);
      }
    }
#pragma unroll
    for (int r = 0; r < 32; ++r) xw[(size_t)(row0 + r) * G3 + g] = acc[r] + bias;
  }
}

// ---------------- layer-1 input projection: [32768,150]@[150,450] ----------------
__global__ __launch_bounds__(512) void k_xw1(const float* __restrict__ in,
                                             const float* __restrict__ WihT,
                                             const float* __restrict__ bih,
                                             float* __restrict__ xw) {
  __shared__ __align__(16) float a_lds[32 * 152];
  const int row0 = blockIdx.x * 32;
  const int tid = threadIdx.x;
  for (int p = tid; p < 32 * HH; p += 512) {
    int r = p / HH, e = p - r * HH;
    a_lds[r * 152 + e] = in[(size_t)(row0 + r) * HH + e];
  }
  __syncthreads();
  const int g = tid;
  if (g < G3) {
    float acc[32];
#pragma unroll
    for (int r = 0; r < 32; ++r) acc[r] = 0.f;
    const float bias = bih[g];
    for (int k = 0; k < 148; k += 4) {
      float w0 = WihT[(k + 0) * G3 + g];
      float w1 = WihT[(k + 1) * G3 + g];
      float w2v = WihT[(k + 2) * G3 + g];
      float w3 = WihT[(k + 3) * G3 + g];
#pragma unroll
      for (int r = 0; r < 32; ++r) {
        const float4 av = *reinterpret_cast<const float4*>(&a_lds[r * 152 + k]);
        acc[r] = fmaf(av.x, w0, acc[r]);
        acc[r] = fmaf(av.y, w1, acc[r]);
        acc[r] = fmaf(av.z, w2v, acc[r]);
        acc[r] = fmaf(av.w, w3, acc[r]);
      }
    }
    {
      float w0 = WihT[148 * G3 + g];
      float w1 = WihT[149 * G3 + g];
#pragma unroll
      for (int r = 0; r < 32; ++r) {
        acc[r] = fmaf(a_lds[r * 152 + 148], w0, acc[r]);
        acc[r] = fmaf(a_lds[r * 152 + 149], w1, acc[r]);
      }
    }
#pragma unroll
    for (int r = 0; r < 32; ++r) xw[(size_t)(row0 + r) * G3 + g] = acc[r] + bias;
  }
}

// ---------------- GRU recurrence: one block (256 thr) per batch element ----------------
// Each thread owns output rows g0=tid and g1=256+tid of Whh (2x150 f32 in
// registers -- __launch_bounds__(256,1) gives the allocator ~512 VGPRs, so no
// spill). h is broadcast via v_readlane from 3 per-wave VGPRs instead of
// per-thread LDS reads.
__global__ __launch_bounds__(256, 1) void k_rec(const float* __restrict__ WhhT,
                                                const float* __restrict__ bhh,
                                                const float* __restrict__ xw,
                                                const int* __restrict__ lengths,
                                                float* __restrict__ out) {
  const int b = blockIdx.x;
  const int tid = threadIdx.x;
  const int lane = tid & 63;
  __shared__ float h_lds[192];          // 150 used; 150..191 stay zero (safe readlane fodder)
  __shared__ float hg_lds[G3];
  const int len = lengths[b];

  const int g0 = tid;                           // < 450 always
  const bool has1 = (256 + tid) < G3;           // tid < 194
  const int g1 = has1 ? (256 + tid) : 0;        // clamped so loads never fault

  float w0[HH], w1[HH];
#pragma unroll
  for (int k = 0; k < HH; ++k) {
    w0[k] = WhhT[k * G3 + g0];
    w1[k] = WhhT[k * G3 + g1];
  }
  const float bias0 = bhh[g0];
  const float bias1 = has1 ? bhh[g1] : 0.f;

  if (tid < 192) h_lds[tid] = 0.f;
  __syncthreads();

  const float* xwb = xw + (size_t)b * TT * G3;
  float* outb = out + (size_t)b * TT * HH;

  for (int t = 0; t < len; ++t) {
    // prefetch xw[t] for the update phase (latency hides under gate compute)
    float xr = 0.f, xz = 0.f, xn = 0.f;
    if (tid < HH) {
      const float* xwt = xwb + (size_t)t * G3;
      xr = xwt[tid]; xz = xwt[tid + HH]; xn = xwt[tid + 2 * HH];
    }
    // each wave pulls h once into 3 VGPRs; inner loop broadcasts via readlane
    const float hv0 = h_lds[lane];
    const float hv1 = h_lds[64 + lane];
    const float hv2 = h_lds[128 + lane];

    float a0 = bias0, a0b = 0.f, a1 = bias1, a1b = 0.f;
#pragma unroll
    for (int k = 0; k < 64; k += 2) {
      const float s0 = bcast_lane(hv0, k);
      const float s1 = bcast_lane(hv0, k + 1);
      a0  = fmaf(w0[k],     s0, a0);
      a1  = fmaf(w1[k],     s0, a1);
      a0b = fmaf(w0[k + 1], s1, a0b);
      a1b = fmaf(w1[k + 1], s1, a1b);
    }
#pragma unroll
    for (int k = 0; k < 64; k += 2) {
      const float s0 = bcast_lane(hv1, k);
      const float s1 = bcast_lane(hv1, k + 1);
      a0  = fmaf(w0[64 + k],     s0, a0);
      a1  = fmaf(w1[64 + k],     s0, a1);
      a0b = fmaf(w0[64 + k + 1], s1, a0b);
      a1b = fmaf(w1[64 + k + 1], s1, a1b);
    }
#pragma unroll
    for (int k = 0; k < 22; k += 2) {
      const float s0 = bcast_lane(hv2, k);
      const float s1 = bcast_lane(hv2, k + 1);
      a0  = fmaf(w0[128 + k],     s0, a0);
      a1  = fmaf(w1[128 + k],     s0, a1);
      a0b = fmaf(w0[128 + k + 1], s1, a0b);
      a1b = fmaf(w1[128 + k + 1], s1, a1b);
    }
    hg_lds[g0] = a0 + a0b;
    if (has1) hg_lds[256 + tid] = a1 + a1b;
    __syncthreads();

    if (tid < HH) {
      const float hr = hg_lds[tid], hz = hg_lds[tid + HH], hn = hg_lds[tid + 2 * HH];
      const float r = sigmoid_f(xr + hr);
      const float z = sigmoid_f(xz + hz);
      const float n = tanh_f(xn + r * hn);
      const float hnew = (1.f - z) * n + z * h_lds[tid];
      h_lds[tid] = hnew;
      outb[(size_t)t * HH + tid] = hnew;
    }
    __syncthreads();
  }
  // pad_packed_sequence pads with zeros past length
  const int rem = (TT - len) * HH;
  float* outp = outb + (size_t)len * HH;
  for (int p = tid; p < rem; p += 256) outp[p] = 0.f;
}

// ---------------- attention scores: tanh(out1 @ W1^T) @ w2^T ----------------
__global__ __launch_bounds__(256) void k_scores(const float* __restrict__ out1,
                                                const float* __restrict__ W1T,
                                                const float* __restrict__ w2,
                                                float* __restrict__ scores) {
  const int row0 = blockIdx.x * 32;
  const int tid = threadIdx.x;
  __shared__ float sc[32];
  if (tid < 32) sc[tid] = 0.f;
  __syncthreads();
  for (int p = tid; p < 32 * AT; p += 256) {
    const int r = p / AT, a = p - r * AT;
    const float* x = out1 + (size_t)(row0 + r) * HH;
    float a0 = 0.f, a1 = 0.f;
    for (int k = 0; k < HH; k += 2) {
      a0 = fmaf(W1T[k * AT + a], x[k], a0);
      a1 = fmaf(W1T[(k + 1) * AT + a], x[k + 1], a1);
    }
    atomicAdd(&sc[r], tanh_f(a0 + a1) * w2[a]);
  }
  __syncthreads();
  if (tid < 32) scores[row0 + tid] = sc[tid];
}

// ---------------- softmax + context + classifier head (per batch) ----------------
__global__ __launch_bounds__(512) void k_final(const float* __restrict__ out1,
                                               const float* __restrict__ scores,
                                               const float* __restrict__ fc1T,
                                               const float* __restrict__ fc1b,
                                               const float* __restrict__ fc2w,
                                               const float* __restrict__ fc2b,
                                               float* __restrict__ logits) {
  const int b = blockIdx.x;
  const int tid = threadIdx.x;
  __shared__ float attn[TT];
  __shared__ float red[16];
  __shared__ float ctx[152];
  __shared__ float h1[152];

  float s = scores[b * TT + tid];
  float m = s;
#pragma unroll
  for (int off = 32; off > 0; off >>= 1) m = fmaxf(m, __shfl_xor(m, off));
  const int wave = tid >> 6;
  if ((tid & 63) == 0) red[wave] = m;
  __syncthreads();
  if (tid == 0) {
    float mm = red[0];
#pragma unroll
    for (int i = 1; i < 8; ++i) mm = fmaxf(mm, red[i]);
    red[8] = mm;
  }
  __syncthreads();
  const float mx = red[8];
  const float e = __expf(s - mx);
  attn[tid] = e;
  float zz = e;
#pragma unroll
  for (int off = 32; off > 0; off >>= 1) zz += __shfl_xor(zz, off);
  if ((tid & 63) == 0) red[wave] = zz;
  __syncthreads();
  if (tid == 0) {
    float ss = 0.f;
#pragma unroll
    for (int i = 0; i < 8; ++i) ss += red[i];
    red[9] = ss;
  }
  __syncthreads();
  const float invZ = 1.f / red[9];

  if (tid < HH) {
    const float* o1b = out1 + (size_t)b * TT * HH;
    float c0 = 0.f, c1 = 0.f, c2 = 0.f, c3 = 0.f;
    for (int t = 0; t < TT; t += 4) {
      c0 = fmaf(attn[t + 0], o1b[(t + 0) * HH + tid], c0);
      c1 = fmaf(attn[t + 1], o1b[(t + 1) * HH + tid], c1);
      c2 = fmaf(attn[t + 2], o1b[(t + 2) * HH + tid], c2);
      c3 = fmaf(attn[t + 3], o1b[(t + 3) * HH + tid], c3);
    }
    ctx[tid] = ((c0 + c1) + (c2 + c3)) * invZ;
  }
  __syncthreads();
  if (tid < HH) {
    float d0 = 0.f, d1 = 0.f;
    for (int k = 0; k < HH; k += 2) {
      d0 = fmaf(fc1T[k * HH + tid], ctx[k], d0);
      d1 = fmaf(fc1T[(k + 1) * HH + tid], ctx[k + 1], d1);
    }
    h1[tid] = fmaxf(d0 + d1 + fc1b[tid], 0.f);
  }
  __syncthreads();
  if (tid == 0) {
    float acc = fc2b[0];
    for (int k = 0; k < HH; ++k) acc = fmaf(fc2w[k], h1[k], acc);
    logits[b] = acc;
  }
}

extern "C" void kernel_launch(void* const* d_in, const int* in_sizes, int n_in,
                              void* d_out, int out_size, void* d_ws, size_t ws_size,
                              hipStream_t stream) {
  const int* texts     = (const int*)d_in[0];
  const int* lengths   = (const int*)d_in[1];
  const float* emb     = (const float*)d_in[2];
  const float* Wih0    = (const float*)d_in[3];
  const float* Whh0    = (const float*)d_in[4];
  const float* bih0    = (const float*)d_in[5];
  const float* bhh0    = (const float*)d_in[6];
  const float* Wih1    = (const float*)d_in[7];
  const float* Whh1    = (const float*)d_in[8];
  const float* bih1    = (const float*)d_in[9];
  const float* bhh1    = (const float*)d_in[10];
  const float* W1      = (const float*)d_in[11];
  const float* w2      = (const float*)d_in[12];
  const float* fc1w    = (const float*)d_in[13];
  const float* fc1b    = (const float*)d_in[14];
  const float* fc2w    = (const float*)d_in[15];
  const float* fc2b    = (const float*)d_in[16];
  float* logits = (float*)d_out;

  float* ws = (float*)d_ws;
  size_t off = 0;
  auto alloc = [&](size_t n) { float* p = ws + off; off += (n + 3) & ~(size_t)3; return p; };
  float* Wih0T  = alloc((size_t)G3 * EE);
  float* Whh0T  = alloc((size_t)G3 * HH);
  float* Wih1T  = alloc((size_t)G3 * HH);
  float* Whh1T  = alloc((size_t)G3 * HH);
  float* W1T    = alloc((size_t)AT * HH);
  float* fc1T   = alloc((size_t)HH * HH);
  float* xwbuf  = alloc((size_t)BB * TT * G3);   // reused for xw0 then xw1
  float* out0   = alloc((size_t)BB * TT * HH);
  float* out1   = alloc((size_t)BB * TT * HH);
  float* scores = alloc((size_t)BB * TT);
  (void)ws_size; (void)in_sizes; (void)n_in; (void)out_size;

  hipLaunchKernelGGL(k_prep, dim3(256), dim3(256), 0, stream,
                     Wih0, Whh0, Wih1, Whh1, W1, fc1w,
                     Wih0T, Whh0T, Wih1T, Whh1T, W1T, fc1T);
  hipLaunchKernelGGL(k_xw0, dim3((BB * TT) / 32), dim3(512), 0, stream, texts, emb, Wih0T, bih0, xwbuf);
  hipLaunchKernelGGL(k_rec, dim3(BB), dim3(256), 0, stream, Whh0T, bhh0, xwbuf, lengths, out0);
  hipLaunchKernelGGL(k_xw1, dim3((BB * TT) / 32), dim3(512), 0, stream, out0, Wih1T, bih1, xwbuf);
  hipLaunchKernelGGL(k_rec, dim3(BB), dim3(256), 0, stream, Whh1T, bhh1, xwbuf, lengths, out1);
  hipLaunchKernelGGL(k_scores, dim3((BB * TT) / 32), dim3(256), 0, stream, out1, W1T, w2, scores);
  hipLaunchKernelGGL(k_final, dim3(BB), dim3(512), 0, stream, out1, scores, fc1T, fc1b, fc2w, fc2b, logits);
}

// Round 3
// 1469.573 us; speedup vs baseline: 1.3254x; 1.3254x over previous
//
#include <hip/hip_runtime.h>

#define TT 512
#define BB 64
#define EE 300
#define HH 150
#define G3 450
#define AT 75

typedef float v2f __attribute__((ext_vector_type(2)));

__device__ __forceinline__ float fast_rcp(float x) { return __builtin_amdgcn_rcpf(x); }
__device__ __forceinline__ float sigmoid_f(float x) { return fast_rcp(1.f + __expf(-x)); }
__device__ __forceinline__ float tanh_f(float x) {
  float e = __expf(2.f * x);          // inf for large x -> result 1; 0 for very negative -> -1
  return 1.f - 2.f * fast_rcp(e + 1.f);
}

// ---------------- transpose prep ----------------
__global__ void k_prep(const float* __restrict__ Wih0, const float* __restrict__ Whh0,
                       const float* __restrict__ Wih1, const float* __restrict__ Whh1,
                       const float* __restrict__ W1,   const float* __restrict__ fc1w,
                       float* __restrict__ Wih0T, float* __restrict__ Whh0T,
                       float* __restrict__ Wih1T, float* __restrict__ Whh1T,
                       float* __restrict__ W1T,   float* __restrict__ fc1T) {
  int tid = blockIdx.x * blockDim.x + threadIdx.x;
  int nt = gridDim.x * blockDim.x;
  for (int i = tid; i < G3 * EE; i += nt) { int r = i / EE, c = i - r * EE; Wih0T[c * G3 + r] = Wih0[i]; }
  for (int i = tid; i < G3 * HH; i += nt) { int r = i / HH, c = i - r * HH; Whh0T[c * G3 + r] = Whh0[i]; }
  for (int i = tid; i < G3 * HH; i += nt) { int r = i / HH, c = i - r * HH; Wih1T[c * G3 + r] = Wih1[i]; }
  for (int i = tid; i < G3 * HH; i += nt) { int r = i / HH, c = i - r * HH; Whh1T[c * G3 + r] = Whh1[i]; }
  for (int i = tid; i < AT * HH; i += nt) { int r = i / HH, c = i - r * HH; W1T[c * AT + r] = W1[i]; }
  for (int i = tid; i < HH * HH; i += nt) { int r = i / HH, c = i - r * HH; fc1T[c * HH + r] = fc1w[i]; }
}

// ---------------- layer-0 input projection: gather + [32768,300]@[300,450] ----------------
__global__ __launch_bounds__(512) void k_xw0(const int* __restrict__ texts,
                                             const float* __restrict__ emb,
                                             const float* __restrict__ WihT,
                                             const float* __restrict__ bih,
                                             float* __restrict__ xw) {
  __shared__ __align__(16) float a_lds[32 * EE];
  const int row0 = blockIdx.x * 32;
  const int tid = threadIdx.x;
  for (int p = tid; p < 32 * EE; p += 512) {
    int r = p / EE, e = p - r * EE;
    int vrow = texts[row0 + r];
    a_lds[p] = emb[(size_t)vrow * EE + e];
  }
  __syncthreads();
  const int g = tid;
  if (g < G3) {
    float acc[32];
#pragma unroll
    for (int r = 0; r < 32; ++r) acc[r] = 0.f;
    const float bias = bih[g];
    for (int k = 0; k < EE; k += 4) {
      float w0 = WihT[(k + 0) * G3 + g];
      float w1 = WihT[(k + 1) * G3 + g];
      float w2v = WihT[(k + 2) * G3 + g];
      float w3 = WihT[(k + 3) * G3 + g];
#pragma unroll
      for (int r = 0; r < 32; ++r) {
        const float4 av = *reinterpret_cast<const float4*>(&a_lds[r * EE + k]);
        acc[r] = fmaf(av.x, w0, acc[r]);
        acc[r] = fmaf(av.y, w1, acc[r]);
        acc[r] = fmaf(av.z, w2v, acc[r]);
        acc[r] = fmaf(av.w, w3, acc[r]);
      }
    }
#pragma unroll
    for (int r = 0; r < 32; ++r) xw[(size_t)(row0 + r) * G3 + g] = acc[r] + bias;
  }
}

// ---------------- layer-1 input projection: [32768,150]@[150,450] ----------------
__global__ __launch_bounds__(512) void k_xw1(const float* __restrict__ in,
                                             const float* __restrict__ WihT,
                                             const float* __restrict__ bih,
                                             float* __restrict__ xw) {
  __shared__ __align__(16) float a_lds[32 * 152];
  const int row0 = blockIdx.x * 32;
  const int tid = threadIdx.x;
  for (int p = tid; p < 32 * HH; p += 512) {
    int r = p / HH, e = p - r * HH;
    a_lds[r * 152 + e] = in[(size_t)(row0 + r) * HH + e];
  }
  __syncthreads();
  const int g = tid;
  if (g < G3) {
    float acc[32];
#pragma unroll
    for (int r = 0; r < 32; ++r) acc[r] = 0.f;
    const float bias = bih[g];
    for (int k = 0; k < 148; k += 4) {
      float w0 = WihT[(k + 0) * G3 + g];
      float w1 = WihT[(k + 1) * G3 + g];
      float w2v = WihT[(k + 2) * G3 + g];
      float w3 = WihT[(k + 3) * G3 + g];
#pragma unroll
      for (int r = 0; r < 32; ++r) {
        const float4 av = *reinterpret_cast<const float4*>(&a_lds[r * 152 + k]);
        acc[r] = fmaf(av.x, w0, acc[r]);
        acc[r] = fmaf(av.y, w1, acc[r]);
        acc[r] = fmaf(av.z, w2v, acc[r]);
        acc[r] = fmaf(av.w, w3, acc[r]);
      }
    }
    {
      float w0 = WihT[148 * G3 + g];
      float w1 = WihT[149 * G3 + g];
#pragma unroll
      for (int r = 0; r < 32; ++r) {
        acc[r] = fmaf(a_lds[r * 152 + 148], w0, acc[r]);
        acc[r] = fmaf(a_lds[r * 152 + 149], w1, acc[r]);
      }
    }
#pragma unroll
    for (int r = 0; r < 32; ++r) xw[(size_t)(row0 + r) * G3 + g] = acc[r] + bias;
  }
}

// ---------------- GRU recurrence: one block (512 thr) per batch element ----------------
// ONE Whh row per thread: 150 f32 in registers -- fits the 256 arch-VGPR cap
// (2-rows/thread = 300 provably cannot fit; that was rounds 1-2's spill).
// __launch_bounds__(512,2): 2 waves/EU -> allocator capped at 256 VGPR, no
// occupancy-heuristic shrink. h broadcast via same-address ds_read_b128
// (conflict-free broadcast); dot product as float2 elementwise-fma so the
// compiler can emit v_pk_fma_f32.
__global__ __launch_bounds__(512, 2) void k_rec(const float* __restrict__ WhhT,
                                                const float* __restrict__ bhh,
                                                const float* __restrict__ xw,
                                                const int* __restrict__ lengths,
                                                float* __restrict__ out) {
  const int b = blockIdx.x;
  const int tid = threadIdx.x;
  __shared__ __align__(16) float h_lds[152];    // 150 used; 150..151 zero pad
  __shared__ float hg_lds[G3];
  const int len = lengths[b];

  const bool active = tid < G3;
  const int g = active ? tid : 0;               // clamp so loads never fault

  v2f w[75];
#pragma unroll
  for (int k = 0; k < 75; ++k) {
    w[k][0] = WhhT[(2 * k) * G3 + g];
    w[k][1] = WhhT[(2 * k + 1) * G3 + g];
  }
  const float bias = bhh[g];
  if (tid < 152) h_lds[tid] = 0.f;
  float h_reg = 0.f;                            // h[tid] for tid<150
  __syncthreads();

  const float* xwb = xw + (size_t)b * TT * G3;
  float* outb = out + (size_t)b * TT * HH;
  const float4* h4 = reinterpret_cast<const float4*>(h_lds);

  for (int t = 0; t < len; ++t) {
    // prefetch xw[t] (global) -- latency hides under the gate matvec
    float xr = 0.f, xz = 0.f, xn = 0.f;
    if (tid < HH) {
      const float* xwt = xwb + (size_t)t * G3;
      xr = xwt[tid]; xz = xwt[tid + HH]; xn = xwt[tid + 2 * HH];
    }
    // hg[g] = bias + sum_k Whh[g,k] * h[k]  (h broadcast from LDS)
    v2f a0 = {0.f, 0.f}, a1 = {0.f, 0.f};
#pragma unroll
    for (int q = 0; q < 37; ++q) {
      const float4 hv = h4[q];
      v2f hx = {hv.x, hv.y};
      v2f hy = {hv.z, hv.w};
      a0 = __builtin_elementwise_fma(w[2 * q], hx, a0);
      a1 = __builtin_elementwise_fma(w[2 * q + 1], hy, a1);
    }
    {
      const float4 hv = h4[37];                 // h[148],h[149],pad,pad
      v2f hx = {hv.x, hv.y};
      a0 = __builtin_elementwise_fma(w[74], hx, a0);
    }
    if (active) hg_lds[g] = bias + (a0[0] + a1[0]) + (a0[1] + a1[1]);
    __syncthreads();

    if (tid < HH) {
      const float hr = hg_lds[tid], hz = hg_lds[tid + HH], hn = hg_lds[tid + 2 * HH];
      const float r = sigmoid_f(xr + hr);
      const float z = sigmoid_f(xz + hz);
      const float n = tanh_f(xn + r * hn);
      const float hnew = (1.f - z) * n + z * h_reg;
      h_reg = hnew;
      h_lds[tid] = hnew;
      outb[(size_t)t * HH + tid] = hnew;
    }
    __syncthreads();
  }
  // pad_packed_sequence pads with zeros past length
  const int rem = (TT - len) * HH;
  float* outp = outb + (size_t)len * HH;
  for (int p = tid; p < rem; p += 512) outp[p] = 0.f;
}

// ---------------- attention scores: tanh(out1 @ W1^T) @ w2^T ----------------
__global__ __launch_bounds__(256) void k_scores(const float* __restrict__ out1,
                                                const float* __restrict__ W1T,
                                                const float* __restrict__ w2,
                                                float* __restrict__ scores) {
  const int row0 = blockIdx.x * 32;
  const int tid = threadIdx.x;
  __shared__ float sc[32];
  if (tid < 32) sc[tid] = 0.f;
  __syncthreads();
  for (int p = tid; p < 32 * AT; p += 256) {
    const int r = p / AT, a = p - r * AT;
    const float* x = out1 + (size_t)(row0 + r) * HH;
    float a0 = 0.f, a1 = 0.f;
    for (int k = 0; k < HH; k += 2) {
      a0 = fmaf(W1T[k * AT + a], x[k], a0);
      a1 = fmaf(W1T[(k + 1) * AT + a], x[k + 1], a1);
    }
    atomicAdd(&sc[r], tanh_f(a0 + a1) * w2[a]);
  }
  __syncthreads();
  if (tid < 32) scores[row0 + tid] = sc[tid];
}

// ---------------- softmax + context + classifier head (per batch) ----------------
__global__ __launch_bounds__(512) void k_final(const float* __restrict__ out1,
                                               const float* __restrict__ scores,
                                               const float* __restrict__ fc1T,
                                               const float* __restrict__ fc1b,
                                               const float* __restrict__ fc2w,
                                               const float* __restrict__ fc2b,
                                               float* __restrict__ logits) {
  const int b = blockIdx.x;
  const int tid = threadIdx.x;
  __shared__ float attn[TT];
  __shared__ float red[16];
  __shared__ float ctx[152];
  __shared__ float h1[152];

  float s = scores[b * TT + tid];
  float m = s;
#pragma unroll
  for (int off = 32; off > 0; off >>= 1) m = fmaxf(m, __shfl_xor(m, off));
  const int wave = tid >> 6;
  if ((tid & 63) == 0) red[wave] = m;
  __syncthreads();
  if (tid == 0) {
    float mm = red[0];
#pragma unroll
    for (int i = 1; i < 8; ++i) mm = fmaxf(mm, red[i]);
    red[8] = mm;
  }
  __syncthreads();
  const float mx = red[8];
  const float e = __expf(s - mx);
  attn[tid] = e;
  float zz = e;
#pragma unroll
  for (int off = 32; off > 0; off >>= 1) zz += __shfl_xor(zz, off);
  if ((tid & 63) == 0) red[wave] = zz;
  __syncthreads();
  if (tid == 0) {
    float ss = 0.f;
#pragma unroll
    for (int i = 0; i < 8; ++i) ss += red[i];
    red[9] = ss;
  }
  __syncthreads();
  const float invZ = 1.f / red[9];

  if (tid < HH) {
    const float* o1b = out1 + (size_t)b * TT * HH;
    float c0 = 0.f, c1 = 0.f, c2 = 0.f, c3 = 0.f;
    for (int t = 0; t < TT; t += 4) {
      c0 = fmaf(attn[t + 0], o1b[(t + 0) * HH + tid], c0);
      c1 = fmaf(attn[t + 1], o1b[(t + 1) * HH + tid], c1);
      c2 = fmaf(attn[t + 2], o1b[(t + 2) * HH + tid], c2);
      c3 = fmaf(attn[t + 3], o1b[(t + 3) * HH + tid], c3);
    }
    ctx[tid] = ((c0 + c1) + (c2 + c3)) * invZ;
  }
  __syncthreads();
  if (tid < HH) {
    float d0 = 0.f, d1 = 0.f;
    for (int k = 0; k < HH; k += 2) {
      d0 = fmaf(fc1T[k * HH + tid], ctx[k], d0);
      d1 = fmaf(fc1T[(k + 1) * HH + tid], ctx[k + 1], d1);
    }
    h1[tid] = fmaxf(d0 + d1 + fc1b[tid], 0.f);
  }
  __syncthreads();
  if (tid == 0) {
    float acc = fc2b[0];
    for (int k = 0; k < HH; ++k) acc = fmaf(fc2w[k], h1[k], acc);
    logits[b] = acc;
  }
}

extern "C" void kernel_launch(void* const* d_in, const int* in_sizes, int n_in,
                              void* d_out, int out_size, void* d_ws, size_t ws_size,
                              hipStream_t stream) {
  const int* texts     = (const int*)d_in[0];
  const int* lengths   = (const int*)d_in[1];
  const float* emb     = (const float*)d_in[2];
  const float* Wih0    = (const float*)d_in[3];
  const float* Whh0    = (const float*)d_in[4];
  const float* bih0    = (const float*)d_in[5];
  const float* bhh0    = (const float*)d_in[6];
  const float* Wih1    = (const float*)d_in[7];
  const float* Whh1    = (const float*)d_in[8];
  const float* bih1    = (const float*)d_in[9];
  const float* bhh1    = (const float*)d_in[10];
  const float* W1      = (const float*)d_in[11];
  const float* w2      = (const float*)d_in[12];
  const float* fc1w    = (const float*)d_in[13];
  const float* fc1b    = (const float*)d_in[14];
  const float* fc2w    = (const float*)d_in[15];
  const float* fc2b    = (const float*)d_in[16];
  float* logits = (float*)d_out;

  float* ws = (float*)d_ws;
  size_t off = 0;
  auto alloc = [&](size_t n) { float* p = ws + off; off += (n + 3) & ~(size_t)3; return p; };
  float* Wih0T  = alloc((size_t)G3 * EE);
  float* Whh0T  = alloc((size_t)G3 * HH);
  float* Wih1T  = alloc((size_t)G3 * HH);
  float* Whh1T  = alloc((size_t)G3 * HH);
  float* W1T    = alloc((size_t)AT * HH);
  float* fc1T   = alloc((size_t)HH * HH);
  float* xwbuf  = alloc((size_t)BB * TT * G3);   // reused for xw0 then xw1
  float* out0   = alloc((size_t)BB * TT * HH);
  float* out1   = alloc((size_t)BB * TT * HH);
  float* scores = alloc((size_t)BB * TT);
  (void)ws_size; (void)in_sizes; (void)n_in; (void)out_size;

  hipLaunchKernelGGL(k_prep, dim3(256), dim3(256), 0, stream,
                     Wih0, Whh0, Wih1, Whh1, W1, fc1w,
                     Wih0T, Whh0T, Wih1T, Whh1T, W1T, fc1T);
  hipLaunchKernelGGL(k_xw0, dim3((BB * TT) / 32), dim3(512), 0, stream, texts, emb, Wih0T, bih0, xwbuf);
  hipLaunchKernelGGL(k_rec, dim3(BB), dim3(512), 0, stream, Whh0T, bhh0, xwbuf, lengths, out0);
  hipLaunchKernelGGL(k_xw1, dim3((BB * TT) / 32), dim3(512), 0, stream, out0, Wih1T, bih1, xwbuf);
  hipLaunchKernelGGL(k_rec, dim3(BB), dim3(512), 0, stream, Whh1T, bhh1, xwbuf, lengths, out1);
  hipLaunchKernelGGL(k_scores, dim3((BB * TT) / 32), dim3(256), 0, stream, out1, W1T, w2, scores);
  hipLaunchKernelGGL(k_final, dim3(BB), dim3(512), 0, stream, out1, scores, fc1T, fc1b, fc2w, fc2b, logits);
}

// Round 4
// 1291.018 us; speedup vs baseline: 1.5088x; 1.1383x over previous
//
#include <hip/hip_runtime.h>

#define TT 512
#define BB 64
#define EE 300
#define HH 150
#define G3 450
#define AT 75

typedef float v2f __attribute__((ext_vector_type(2)));

__device__ __forceinline__ float fast_rcp(float x) { return __builtin_amdgcn_rcpf(x); }
__device__ __forceinline__ float sigmoid_f(float x) { return fast_rcp(1.f + __expf(-x)); }
__device__ __forceinline__ float tanh_f(float x) {
  float e = __expf(2.f * x);          // inf for large x -> result 1; 0 for very negative -> -1
  return 1.f - 2.f * fast_rcp(e + 1.f);
}

// ---------------- transpose prep ----------------
__global__ void k_prep(const float* __restrict__ Wih0, const float* __restrict__ Whh0,
                       const float* __restrict__ Wih1, const float* __restrict__ Whh1,
                       const float* __restrict__ W1,   const float* __restrict__ fc1w,
                       float* __restrict__ Wih0T, float* __restrict__ Whh0T,
                       float* __restrict__ Wih1T, float* __restrict__ Whh1T,
                       float* __restrict__ W1T,   float* __restrict__ fc1T) {
  int tid = blockIdx.x * blockDim.x + threadIdx.x;
  int nt = gridDim.x * blockDim.x;
  for (int i = tid; i < G3 * EE; i += nt) { int r = i / EE, c = i - r * EE; Wih0T[c * G3 + r] = Wih0[i]; }
  for (int i = tid; i < G3 * HH; i += nt) { int r = i / HH, c = i - r * HH; Whh0T[c * G3 + r] = Whh0[i]; }
  for (int i = tid; i < G3 * HH; i += nt) { int r = i / HH, c = i - r * HH; Wih1T[c * G3 + r] = Wih1[i]; }
  for (int i = tid; i < G3 * HH; i += nt) { int r = i / HH, c = i - r * HH; Whh1T[c * G3 + r] = Whh1[i]; }
  for (int i = tid; i < AT * HH; i += nt) { int r = i / HH, c = i - r * HH; W1T[c * AT + r] = W1[i]; }
  for (int i = tid; i < HH * HH; i += nt) { int r = i / HH, c = i - r * HH; fc1T[c * HH + r] = fc1w[i]; }
}

// ---------------- layer-0 input projection: gather + [32768,300]@[300,450] ----------------
__global__ __launch_bounds__(512) void k_xw0(const int* __restrict__ texts,
                                             const float* __restrict__ emb,
                                             const float* __restrict__ WihT,
                                             const float* __restrict__ bih,
                                             float* __restrict__ xw) {
  __shared__ __align__(16) float a_lds[32 * EE];
  const int row0 = blockIdx.x * 32;
  const int tid = threadIdx.x;
  for (int p = tid; p < 32 * EE; p += 512) {
    int r = p / EE, e = p - r * EE;
    int vrow = texts[row0 + r];
    a_lds[p] = emb[(size_t)vrow * EE + e];
  }
  __syncthreads();
  const int g = tid;
  if (g < G3) {
    float acc[32];
#pragma unroll
    for (int r = 0; r < 32; ++r) acc[r] = 0.f;
    const float bias = bih[g];
    for (int k = 0; k < EE; k += 4) {
      float w0 = WihT[(k + 0) * G3 + g];
      float w1 = WihT[(k + 1) * G3 + g];
      float w2v = WihT[(k + 2) * G3 + g];
      float w3 = WihT[(k + 3) * G3 + g];
#pragma unroll
      for (int r = 0; r < 32; ++r) {
        const float4 av = *reinterpret_cast<const float4*>(&a_lds[r * EE + k]);
        acc[r] = fmaf(av.x, w0, acc[r]);
        acc[r] = fmaf(av.y, w1, acc[r]);
        acc[r] = fmaf(av.z, w2v, acc[r]);
        acc[r] = fmaf(av.w, w3, acc[r]);
      }
    }
#pragma unroll
    for (int r = 0; r < 32; ++r) xw[(size_t)(row0 + r) * G3 + g] = acc[r] + bias;
  }
}

// ---------------- layer-1 input projection: [32768,150]@[150,450] ----------------
__global__ __launch_bounds__(512) void k_xw1(const float* __restrict__ in,
                                             const float* __restrict__ WihT,
                                             const float* __restrict__ bih,
                                             float* __restrict__ xw) {
  __shared__ __align__(16) float a_lds[32 * 152];
  const int row0 = blockIdx.x * 32;
  const int tid = threadIdx.x;
  for (int p = tid; p < 32 * HH; p += 512) {
    int r = p / HH, e = p - r * HH;
    a_lds[r * 152 + e] = in[(size_t)(row0 + r) * HH + e];
  }
  __syncthreads();
  const int g = tid;
  if (g < G3) {
    float acc[32];
#pragma unroll
    for (int r = 0; r < 32; ++r) acc[r] = 0.f;
    const float bias = bih[g];
    for (int k = 0; k < 148; k += 4) {
      float w0 = WihT[(k + 0) * G3 + g];
      float w1 = WihT[(k + 1) * G3 + g];
      float w2v = WihT[(k + 2) * G3 + g];
      float w3 = WihT[(k + 3) * G3 + g];
#pragma unroll
      for (int r = 0; r < 32; ++r) {
        const float4 av = *reinterpret_cast<const float4*>(&a_lds[r * 152 + k]);
        acc[r] = fmaf(av.x, w0, acc[r]);
        acc[r] = fmaf(av.y, w1, acc[r]);
        acc[r] = fmaf(av.z, w2v, acc[r]);
        acc[r] = fmaf(av.w, w3, acc[r]);
      }
    }
    {
      float w0 = WihT[148 * G3 + g];
      float w1 = WihT[149 * G3 + g];
#pragma unroll
      for (int r = 0; r < 32; ++r) {
        acc[r] = fmaf(a_lds[r * 152 + 148], w0, acc[r]);
        acc[r] = fmaf(a_lds[r * 152 + 149], w1, acc[r]);
      }
    }
#pragma unroll
    for (int r = 0; r < 32; ++r) xw[(size_t)(row0 + r) * G3 + g] = acc[r] + bias;
  }
}

// ---------------- GRU recurrence: one block (512 thr) per batch element ----------------
// ONE Whh row per thread (150 f32). Round-3 lesson: without pinning, the
// compiler REMATERIALIZES the weight loads into the t-loop (VGPR_Count=92)
// and the kernel becomes L2-BW-bound re-streaming 300KB/step. The asm
// laundering below makes each weight pair originate from an opaque asm, so
// it cannot be re-loaded -- forcing true register residency (~170 VGPR,
// fits the 256 cap at __launch_bounds__(512,2)).
__global__ __launch_bounds__(512, 2) void k_rec(const float* __restrict__ WhhT,
                                                const float* __restrict__ bhh,
                                                const float* __restrict__ xw,
                                                const int* __restrict__ lengths,
                                                float* __restrict__ out) {
  const int b = blockIdx.x;
  const int tid = threadIdx.x;
  __shared__ __align__(16) float h_lds[152];    // 150 used; 150..151 zero pad
  __shared__ float hg_lds[G3];
  const int len = lengths[b];

  const bool active = tid < G3;
  const int g = active ? tid : 0;               // clamp so loads never fault

  v2f w[75];
#pragma unroll
  for (int k = 0; k < 75; ++k) {
    w[k][0] = WhhT[(2 * k) * G3 + g];
    w[k][1] = WhhT[(2 * k + 1) * G3 + g];
  }
  // Pin: value now defined by opaque asm -> not rematerializable.
#pragma unroll
  for (int k = 0; k < 75; ++k) asm volatile("" : "+v"(w[k]));

  const float bias = bhh[g];
  if (tid < 152) h_lds[tid] = 0.f;
  float h_reg = 0.f;                            // h[tid] for tid<150
  __syncthreads();

  const float* xwb = xw + (size_t)b * TT * G3;
  float* outb = out + (size_t)b * TT * HH;
  const float4* h4 = reinterpret_cast<const float4*>(h_lds);

  for (int t = 0; t < len; ++t) {
    // prefetch xw[t] (global) -- latency hides under the gate matvec
    float xr = 0.f, xz = 0.f, xn = 0.f;
    if (tid < HH) {
      const float* xwt = xwb + (size_t)t * G3;
      xr = xwt[tid]; xz = xwt[tid + HH]; xn = xwt[tid + 2 * HH];
    }
    // hg[g] = bias + sum_k Whh[g,k] * h[k]  (h broadcast from LDS)
    v2f a0 = {0.f, 0.f}, a1 = {0.f, 0.f};
#pragma unroll
    for (int q = 0; q < 37; ++q) {
      const float4 hv = h4[q];
      v2f hx = {hv.x, hv.y};
      v2f hy = {hv.z, hv.w};
      a0 = __builtin_elementwise_fma(w[2 * q], hx, a0);
      a1 = __builtin_elementwise_fma(w[2 * q + 1], hy, a1);
    }
    {
      const float4 hv = h4[37];                 // h[148],h[149],pad,pad
      v2f hx = {hv.x, hv.y};
      a0 = __builtin_elementwise_fma(w[74], hx, a0);
    }
    if (active) hg_lds[g] = bias + (a0[0] + a1[0]) + (a0[1] + a1[1]);
    __syncthreads();

    if (tid < HH) {
      const float hr = hg_lds[tid], hz = hg_lds[tid + HH], hn = hg_lds[tid + 2 * HH];
      const float r = sigmoid_f(xr + hr);
      const float z = sigmoid_f(xz + hz);
      const float n = tanh_f(xn + r * hn);
      const float hnew = (1.f - z) * n + z * h_reg;
      h_reg = hnew;
      h_lds[tid] = hnew;
      outb[(size_t)t * HH + tid] = hnew;
    }
    __syncthreads();
  }
  // pad_packed_sequence pads with zeros past length
  const int rem = (TT - len) * HH;
  float* outp = outb + (size_t)len * HH;
  for (int p = tid; p < rem; p += 512) outp[p] = 0.f;
}

// ---------------- attention scores: tanh(out1 @ W1^T) @ w2^T ----------------
__global__ __launch_bounds__(256) void k_scores(const float* __restrict__ out1,
                                                const float* __restrict__ W1T,
                                                const float* __restrict__ w2,
                                                float* __restrict__ scores) {
  const int row0 = blockIdx.x * 32;
  const int tid = threadIdx.x;
  __shared__ float sc[32];
  if (tid < 32) sc[tid] = 0.f;
  __syncthreads();
  for (int p = tid; p < 32 * AT; p += 256) {
    const int r = p / AT, a = p - r * AT;
    const float* x = out1 + (size_t)(row0 + r) * HH;
    float a0 = 0.f, a1 = 0.f;
    for (int k = 0; k < HH; k += 2) {
      a0 = fmaf(W1T[k * AT + a], x[k], a0);
      a1 = fmaf(W1T[(k + 1) * AT + a], x[k + 1], a1);
    }
    atomicAdd(&sc[r], tanh_f(a0 + a1) * w2[a]);
  }
  __syncthreads();
  if (tid < 32) scores[row0 + tid] = sc[tid];
}

// ---------------- softmax + context + classifier head (per batch) ----------------
__global__ __launch_bounds__(512) void k_final(const float* __restrict__ out1,
                                               const float* __restrict__ scores,
                                               const float* __restrict__ fc1T,
                                               const float* __restrict__ fc1b,
                                               const float* __restrict__ fc2w,
                                               const float* __restrict__ fc2b,
                                               float* __restrict__ logits) {
  const int b = blockIdx.x;
  const int tid = threadIdx.x;
  __shared__ float attn[TT];
  __shared__ float red[16];
  __shared__ float ctx[152];
  __shared__ float h1[152];

  float s = scores[b * TT + tid];
  float m = s;
#pragma unroll
  for (int off = 32; off > 0; off >>= 1) m = fmaxf(m, __shfl_xor(m, off));
  const int wave = tid >> 6;
  if ((tid & 63) == 0) red[wave] = m;
  __syncthreads();
  if (tid == 0) {
    float mm = red[0];
#pragma unroll
    for (int i = 1; i < 8; ++i) mm = fmaxf(mm, red[i]);
    red[8] = mm;
  }
  __syncthreads();
  const float mx = red[8];
  const float e = __expf(s - mx);
  attn[tid] = e;
  float zz = e;
#pragma unroll
  for (int off = 32; off > 0; off >>= 1) zz += __shfl_xor(zz, off);
  if ((tid & 63) == 0) red[wave] = zz;
  __syncthreads();
  if (tid == 0) {
    float ss = 0.f;
#pragma unroll
    for (int i = 0; i < 8; ++i) ss += red[i];
    red[9] = ss;
  }
  __syncthreads();
  const float invZ = 1.f / red[9];

  if (tid < HH) {
    const float* o1b = out1 + (size_t)b * TT * HH;
    float c0 = 0.f, c1 = 0.f, c2 = 0.f, c3 = 0.f;
    for (int t = 0; t < TT; t += 4) {
      c0 = fmaf(attn[t + 0], o1b[(t + 0) * HH + tid], c0);
      c1 = fmaf(attn[t + 1], o1b[(t + 1) * HH + tid], c1);
      c2 = fmaf(attn[t + 2], o1b[(t + 2) * HH + tid], c2);
      c3 = fmaf(attn[t + 3], o1b[(t + 3) * HH + tid], c3);
    }
    ctx[tid] = ((c0 + c1) + (c2 + c3)) * invZ;
  }
  __syncthreads();
  if (tid < HH) {
    float d0 = 0.f, d1 = 0.f;
    for (int k = 0; k < HH; k += 2) {
      d0 = fmaf(fc1T[k * HH + tid], ctx[k], d0);
      d1 = fmaf(fc1T[(k + 1) * HH + tid], ctx[k + 1], d1);
    }
    h1[tid] = fmaxf(d0 + d1 + fc1b[tid], 0.f);
  }
  __syncthreads();
  if (tid == 0) {
    float acc = fc2b[0];
    for (int k = 0; k < HH; ++k) acc = fmaf(fc2w[k], h1[k], acc);
    logits[b] = acc;
  }
}

extern "C" void kernel_launch(void* const* d_in, const int* in_sizes, int n_in,
                              void* d_out, int out_size, void* d_ws, size_t ws_size,
                              hipStream_t stream) {
  const int* texts     = (const int*)d_in[0];
  const int* lengths   = (const int*)d_in[1];
  const float* emb     = (const float*)d_in[2];
  const float* Wih0    = (const float*)d_in[3];
  const float* Whh0    = (const float*)d_in[4];
  const float* bih0    = (const float*)d_in[5];
  const float* bhh0    = (const float*)d_in[6];
  const float* Wih1    = (const float*)d_in[7];
  const float* Whh1    = (const float*)d_in[8];
  const float* bih1    = (const float*)d_in[9];
  const float* bhh1    = (const float*)d_in[10];
  const float* W1      = (const float*)d_in[11];
  const float* w2      = (const float*)d_in[12];
  const float* fc1w    = (const float*)d_in[13];
  const float* fc1b    = (const float*)d_in[14];
  const float* fc2w    = (const float*)d_in[15];
  const float* fc2b    = (const float*)d_in[16];
  float* logits = (float*)d_out;

  float* ws = (float*)d_ws;
  size_t off = 0;
  auto alloc = [&](size_t n) { float* p = ws + off; off += (n + 3) & ~(size_t)3; return p; };
  float* Wih0T  = alloc((size_t)G3 * EE);
  float* Whh0T  = alloc((size_t)G3 * HH);
  float* Wih1T  = alloc((size_t)G3 * HH);
  float* Whh1T  = alloc((size_t)G3 * HH);
  float* W1T    = alloc((size_t)AT * HH);
  float* fc1T   = alloc((size_t)HH * HH);
  float* xwbuf  = alloc((size_t)BB * TT * G3);   // reused for xw0 then xw1
  float* out0   = alloc((size_t)BB * TT * HH);
  float* out1   = alloc((size_t)BB * TT * HH);
  float* scores = alloc((size_t)BB * TT);
  (void)ws_size; (void)in_sizes; (void)n_in; (void)out_size;

  hipLaunchKernelGGL(k_prep, dim3(256), dim3(256), 0, stream,
                     Wih0, Whh0, Wih1, Whh1, W1, fc1w,
                     Wih0T, Whh0T, Wih1T, Whh1T, W1T, fc1T);
  hipLaunchKernelGGL(k_xw0, dim3((BB * TT) / 32), dim3(512), 0, stream, texts, emb, Wih0T, bih0, xwbuf);
  hipLaunchKernelGGL(k_rec, dim3(BB), dim3(512), 0, stream, Whh0T, bhh0, xwbuf, lengths, out0);
  hipLaunchKernelGGL(k_xw1, dim3((BB * TT) / 32), dim3(512), 0, stream, out0, Wih1T, bih1, xwbuf);
  hipLaunchKernelGGL(k_rec, dim3(BB), dim3(512), 0, stream, Whh1T, bhh1, xwbuf, lengths, out1);
  hipLaunchKernelGGL(k_scores, dim3((BB * TT) / 32), dim3(256), 0, stream, out1, W1T, w2, scores);
  hipLaunchKernelGGL(k_final, dim3(BB), dim3(512), 0, stream, out1, scores, fc1T, fc1b, fc2w, fc2b, logits);
}

// Round 5
// 1138.663 us; speedup vs baseline: 1.7106x; 1.1338x over previous
//
#include <hip/hip_runtime.h>

#define TT 512
#define BB 64
#define EE 300
#define HH 150
#define G3 450
#define AT 75
#define NW 28          // v2f pairs per row-slice (56-float h window)

typedef float v2f __attribute__((ext_vector_type(2)));

__device__ __forceinline__ float fast_rcp(float x) { return __builtin_amdgcn_rcpf(x); }
__device__ __forceinline__ float sigmoid_f(float x) { return fast_rcp(1.f + __expf(-x)); }
__device__ __forceinline__ float tanh_f(float x) {
  float e = __expf(2.f * x);          // inf for large x -> result 1; 0 for very negative -> -1
  return 1.f - 2.f * fast_rcp(e + 1.f);
}

// ---------------- transpose prep ----------------
__global__ void k_prep(const float* __restrict__ Wih0, const float* __restrict__ Whh0,
                       const float* __restrict__ Wih1, const float* __restrict__ Whh1,
                       const float* __restrict__ W1,   const float* __restrict__ fc1w,
                       float* __restrict__ Wih0T, float* __restrict__ Whh0T,
                       float* __restrict__ Wih1T, float* __restrict__ Whh1T,
                       float* __restrict__ W1T,   float* __restrict__ fc1T) {
  int tid = blockIdx.x * blockDim.x + threadIdx.x;
  int nt = gridDim.x * blockDim.x;
  for (int i = tid; i < G3 * EE; i += nt) { int r = i / EE, c = i - r * EE; Wih0T[c * G3 + r] = Wih0[i]; }
  for (int i = tid; i < G3 * HH; i += nt) { int r = i / HH, c = i - r * HH; Whh0T[c * G3 + r] = Whh0[i]; }
  for (int i = tid; i < G3 * HH; i += nt) { int r = i / HH, c = i - r * HH; Wih1T[c * G3 + r] = Wih1[i]; }
  for (int i = tid; i < G3 * HH; i += nt) { int r = i / HH, c = i - r * HH; Whh1T[c * G3 + r] = Whh1[i]; }
  for (int i = tid; i < AT * HH; i += nt) { int r = i / HH, c = i - r * HH; W1T[c * AT + r] = W1[i]; }
  for (int i = tid; i < HH * HH; i += nt) { int r = i / HH, c = i - r * HH; fc1T[c * HH + r] = fc1w[i]; }
}

// ---------------- layer-0 input projection: gather + [32768,300]@[300,450] ----------------
__global__ __launch_bounds__(512) void k_xw0(const int* __restrict__ texts,
                                             const float* __restrict__ emb,
                                             const float* __restrict__ WihT,
                                             const float* __restrict__ bih,
                                             float* __restrict__ xw) {
  __shared__ __align__(16) float a_lds[32 * EE];
  const int row0 = blockIdx.x * 32;
  const int tid = threadIdx.x;
  for (int p = tid; p < 32 * EE; p += 512) {
    int r = p / EE, e = p - r * EE;
    int vrow = texts[row0 + r];
    a_lds[p] = emb[(size_t)vrow * EE + e];
  }
  __syncthreads();
  const int g = tid;
  if (g < G3) {
    float acc[32];
#pragma unroll
    for (int r = 0; r < 32; ++r) acc[r] = 0.f;
    const float bias = bih[g];
    for (int k = 0; k < EE; k += 4) {
      float w0 = WihT[(k + 0) * G3 + g];
      float w1 = WihT[(k + 1) * G3 + g];
      float w2v = WihT[(k + 2) * G3 + g];
      float w3 = WihT[(k + 3) * G3 + g];
#pragma unroll
      for (int r = 0; r < 32; ++r) {
        const float4 av = *reinterpret_cast<const float4*>(&a_lds[r * EE + k]);
        acc[r] = fmaf(av.x, w0, acc[r]);
        acc[r] = fmaf(av.y, w1, acc[r]);
        acc[r] = fmaf(av.z, w2v, acc[r]);
        acc[r] = fmaf(av.w, w3, acc[r]);
      }
    }
#pragma unroll
    for (int r = 0; r < 32; ++r) xw[(size_t)(row0 + r) * G3 + g] = acc[r] + bias;
  }
}

// ---------------- layer-1 input projection: [32768,150]@[150,450] ----------------
__global__ __launch_bounds__(512) void k_xw1(const float* __restrict__ in,
                                             const float* __restrict__ WihT,
                                             const float* __restrict__ bih,
                                             float* __restrict__ xw) {
  __shared__ __align__(16) float a_lds[32 * 152];
  const int row0 = blockIdx.x * 32;
  const int tid = threadIdx.x;
  for (int p = tid; p < 32 * HH; p += 512) {
    int r = p / HH, e = p - r * HH;
    a_lds[r * 152 + e] = in[(size_t)(row0 + r) * HH + e];
  }
  __syncthreads();
  const int g = tid;
  if (g < G3) {
    float acc[32];
#pragma unroll
    for (int r = 0; r < 32; ++r) acc[r] = 0.f;
    const float bias = bih[g];
    for (int k = 0; k < 148; k += 4) {
      float w0 = WihT[(k + 0) * G3 + g];
      float w1 = WihT[(k + 1) * G3 + g];
      float w2v = WihT[(k + 2) * G3 + g];
      float w3 = WihT[(k + 3) * G3 + g];
#pragma unroll
      for (int r = 0; r < 32; ++r) {
        const float4 av = *reinterpret_cast<const float4*>(&a_lds[r * 152 + k]);
        acc[r] = fmaf(av.x, w0, acc[r]);
        acc[r] = fmaf(av.y, w1, acc[r]);
        acc[r] = fmaf(av.z, w2v, acc[r]);
        acc[r] = fmaf(av.w, w3, acc[r]);
      }
    }
    {
      float w0 = WihT[148 * G3 + g];
      float w1 = WihT[149 * G3 + g];
#pragma unroll
      for (int r = 0; r < 32; ++r) {
        acc[r] = fmaf(a_lds[r * 152 + 148], w0, acc[r]);
        acc[r] = fmaf(a_lds[r * 152 + 149], w1, acc[r]);
      }
    }
#pragma unroll
    for (int r = 0; r < 32; ++r) xw[(size_t)(row0 + r) * G3 + g] = acc[r] + bias;
  }
}

// ---------------- GRU recurrence: one block (512 thr) per batch element ----------------
// Round-4 lesson: row-per-thread makes EVERY thread read ALL of h -> 270KB/step
// of LDS broadcast (the real bottleneck). New decomposition: thread (g, j)
// owns ALL THREE gate rows {j, j+150, j+300} restricted to k-slice g
// (3 slices of ~50). h broadcast volume drops 3x (each thread reads a 56-float
// window, used for 3 rows); weights = 3*56 = 168 f32/thread -> ~200 VGPR,
// genuinely register-resident (no 256-cap violation, no spill). Slices 1,2
// write partials to LDS; slice 0 combines + gates + h update.
__global__ __launch_bounds__(512, 2) void k_rec(const float* __restrict__ WhhT,
                                                const float* __restrict__ bhh,
                                                const float* __restrict__ xw,
                                                const int* __restrict__ lengths,
                                                float* __restrict__ out) {
  const int b = blockIdx.x;
  const int tid = threadIdx.x;
  __shared__ __align__(16) float h_lds[152];      // 150 used; pad zeros
  __shared__ float part[2][G3 + 6];
  const int len = lengths[b];

  int g = tid / 150;                               // 0,1,2 worker slices; 3 = inactive
  const bool worker = g < 3;
  const int gg = worker ? g : 2;
  const int j = worker ? (tid - 150 * g) : 0;
  const int kreal_end = (gg == 2) ? 150 : 48 * (gg + 1);
  const int h4base = 12 * gg;                      // float4 index of window start (48g/4)

  // weights: rows {j, j+150, j+300}, k-window [48g, 48g+56), zero-padded
  v2f w[3][NW];
#pragma unroll
  for (int r = 0; r < 3; ++r) {
    const int row = j + 150 * r;
#pragma unroll
    for (int q = 0; q < NW; ++q) {
      const int k0 = 48 * gg + 2 * q;
      const int k1 = k0 + 1;
      w[r][q][0] = (worker && k0 < kreal_end) ? WhhT[k0 * G3 + row] : 0.f;
      w[r][q][1] = (worker && k1 < kreal_end) ? WhhT[k1 * G3 + row] : 0.f;
    }
  }
  const float bias_r = bhh[j];
  const float bias_z = bhh[j + 150];
  const float bias_n = bhh[j + 300];

  for (int p = tid; p < 152; p += 512) h_lds[p] = 0.f;
  float h_reg = 0.f;                               // h[j] for g0 threads
  __syncthreads();

  const float* xwb = xw + (size_t)b * TT * G3;
  float* outb = out + (size_t)b * TT * HH;
  const float4* h4 = reinterpret_cast<const float4*>(h_lds);

  for (int t = 0; t < len; ++t) {
    // prefetch xw[t] (only the update threads need it; hides under gate matvec)
    float xr = 0.f, xz = 0.f, xn = 0.f;
    if (tid < HH) {
      const float* xwt = xwb + (size_t)t * G3;
      xr = xwt[tid]; xz = xwt[tid + HH]; xn = xwt[tid + 2 * HH];
    }
    // 3-row gate matvec over this thread's k-window (14 x b128 broadcast reads)
    v2f ar0 = {0.f, 0.f}, ar1 = {0.f, 0.f};
    v2f az0 = {0.f, 0.f}, az1 = {0.f, 0.f};
    v2f an0 = {0.f, 0.f}, an1 = {0.f, 0.f};
#pragma unroll
    for (int q = 0; q < 14; ++q) {
      const float4 hv = h4[h4base + q];
      const v2f hx = {hv.x, hv.y};
      const v2f hy = {hv.z, hv.w};
      ar0 = __builtin_elementwise_fma(w[0][2 * q],     hx, ar0);
      ar1 = __builtin_elementwise_fma(w[0][2 * q + 1], hy, ar1);
      az0 = __builtin_elementwise_fma(w[1][2 * q],     hx, az0);
      az1 = __builtin_elementwise_fma(w[1][2 * q + 1], hy, az1);
      an0 = __builtin_elementwise_fma(w[2][2 * q],     hx, an0);
      an1 = __builtin_elementwise_fma(w[2][2 * q + 1], hy, an1);
    }
    const float pr = (ar0[0] + ar0[1]) + (ar1[0] + ar1[1]);
    const float pz = (az0[0] + az0[1]) + (az1[0] + az1[1]);
    const float pn = (an0[0] + an0[1]) + (an1[0] + an1[1]);
    if (worker && g > 0) {
      part[g - 1][j] = pr;
      part[g - 1][j + 150] = pz;
      part[g - 1][j + 300] = pn;
    }
    __syncthreads();

    if (tid < HH) {
      const float hr = pr + part[0][tid] + part[1][tid] + bias_r;
      const float hz = pz + part[0][tid + 150] + part[1][tid + 150] + bias_z;
      const float hn = pn + part[0][tid + 300] + part[1][tid + 300] + bias_n;
      const float r = sigmoid_f(xr + hr);
      const float z = sigmoid_f(xz + hz);
      const float n = tanh_f(xn + r * hn);
      const float hnew = (1.f - z) * n + z * h_reg;
      h_reg = hnew;
      h_lds[tid] = hnew;
      outb[(size_t)t * HH + tid] = hnew;
    }
    __syncthreads();
  }
  // pad_packed_sequence pads with zeros past length
  const int rem = (TT - len) * HH;
  float* outp = outb + (size_t)len * HH;
  for (int p = tid; p < rem; p += 512) outp[p] = 0.f;
}

// ---------------- attention scores: tanh(out1 @ W1^T) @ w2^T ----------------
__global__ __launch_bounds__(256) void k_scores(const float* __restrict__ out1,
                                                const float* __restrict__ W1T,
                                                const float* __restrict__ w2,
                                                float* __restrict__ scores) {
  const int row0 = blockIdx.x * 32;
  const int tid = threadIdx.x;
  __shared__ float sc[32];
  if (tid < 32) sc[tid] = 0.f;
  __syncthreads();
  for (int p = tid; p < 32 * AT; p += 256) {
    const int r = p / AT, a = p - r * AT;
    const float* x = out1 + (size_t)(row0 + r) * HH;
    float a0 = 0.f, a1 = 0.f;
    for (int k = 0; k < HH; k += 2) {
      a0 = fmaf(W1T[k * AT + a], x[k], a0);
      a1 = fmaf(W1T[(k + 1) * AT + a], x[k + 1], a1);
    }
    atomicAdd(&sc[r], tanh_f(a0 + a1) * w2[a]);
  }
  __syncthreads();
  if (tid < 32) scores[row0 + tid] = sc[tid];
}

// ---------------- softmax + context + classifier head (per batch) ----------------
__global__ __launch_bounds__(512) void k_final(const float* __restrict__ out1,
                                               const float* __restrict__ scores,
                                               const float* __restrict__ fc1T,
                                               const float* __restrict__ fc1b,
                                               const float* __restrict__ fc2w,
                                               const float* __restrict__ fc2b,
                                               float* __restrict__ logits) {
  const int b = blockIdx.x;
  const int tid = threadIdx.x;
  __shared__ float attn[TT];
  __shared__ float red[16];
  __shared__ float ctx[152];
  __shared__ float h1[152];

  float s = scores[b * TT + tid];
  float m = s;
#pragma unroll
  for (int off = 32; off > 0; off >>= 1) m = fmaxf(m, __shfl_xor(m, off));
  const int wave = tid >> 6;
  if ((tid & 63) == 0) red[wave] = m;
  __syncthreads();
  if (tid == 0) {
    float mm = red[0];
#pragma unroll
    for (int i = 1; i < 8; ++i) mm = fmaxf(mm, red[i]);
    red[8] = mm;
  }
  __syncthreads();
  const float mx = red[8];
  const float e = __expf(s - mx);
  attn[tid] = e;
  float zz = e;
#pragma unroll
  for (int off = 32; off > 0; off >>= 1) zz += __shfl_xor(zz, off);
  if ((tid & 63) == 0) red[wave] = zz;
  __syncthreads();
  if (tid == 0) {
    float ss = 0.f;
#pragma unroll
    for (int i = 0; i < 8; ++i) ss += red[i];
    red[9] = ss;
  }
  __syncthreads();
  const float invZ = 1.f / red[9];

  if (tid < HH) {
    const float* o1b = out1 + (size_t)b * TT * HH;
    float c0 = 0.f, c1 = 0.f, c2 = 0.f, c3 = 0.f;
    for (int t = 0; t < TT; t += 4) {
      c0 = fmaf(attn[t + 0], o1b[(t + 0) * HH + tid], c0);
      c1 = fmaf(attn[t + 1], o1b[(t + 1) * HH + tid], c1);
      c2 = fmaf(attn[t + 2], o1b[(t + 2) * HH + tid], c2);
      c3 = fmaf(attn[t + 3], o1b[(t + 3) * HH + tid], c3);
    }
    ctx[tid] = ((c0 + c1) + (c2 + c3)) * invZ;
  }
  __syncthreads();
  if (tid < HH) {
    float d0 = 0.f, d1 = 0.f;
    for (int k = 0; k < HH; k += 2) {
      d0 = fmaf(fc1T[k * HH + tid], ctx[k], d0);
      d1 = fmaf(fc1T[(k + 1) * HH + tid], ctx[k + 1], d1);
    }
    h1[tid] = fmaxf(d0 + d1 + fc1b[tid], 0.f);
  }
  __syncthreads();
  if (tid == 0) {
    float acc = fc2b[0];
    for (int k = 0; k < HH; ++k) acc = fmaf(fc2w[k], h1[k], acc);
    logits[b] = acc;
  }
}

extern "C" void kernel_launch(void* const* d_in, const int* in_sizes, int n_in,
                              void* d_out, int out_size, void* d_ws, size_t ws_size,
                              hipStream_t stream) {
  const int* texts     = (const int*)d_in[0];
  const int* lengths   = (const int*)d_in[1];
  const float* emb     = (const float*)d_in[2];
  const float* Wih0    = (const float*)d_in[3];
  const float* Whh0    = (const float*)d_in[4];
  const float* bih0    = (const float*)d_in[5];
  const float* bhh0    = (const float*)d_in[6];
  const float* Wih1    = (const float*)d_in[7];
  const float* Whh1    = (const float*)d_in[8];
  const float* bih1    = (const float*)d_in[9];
  const float* bhh1    = (const float*)d_in[10];
  const float* W1      = (const float*)d_in[11];
  const float* w2      = (const float*)d_in[12];
  const float* fc1w    = (const float*)d_in[13];
  const float* fc1b    = (const float*)d_in[14];
  const float* fc2w    = (const float*)d_in[15];
  const float* fc2b    = (const float*)d_in[16];
  float* logits = (float*)d_out;

  float* ws = (float*)d_ws;
  size_t off = 0;
  auto alloc = [&](size_t n) { float* p = ws + off; off += (n + 3) & ~(size_t)3; return p; };
  float* Wih0T  = alloc((size_t)G3 * EE);
  float* Whh0T  = alloc((size_t)G3 * HH);
  float* Wih1T  = alloc((size_t)G3 * HH);
  float* Whh1T  = alloc((size_t)G3 * HH);
  float* W1T    = alloc((size_t)AT * HH);
  float* fc1T   = alloc((size_t)HH * HH);
  float* xwbuf  = alloc((size_t)BB * TT * G3);   // reused for xw0 then xw1
  float* out0   = alloc((size_t)BB * TT * HH);
  float* out1   = alloc((size_t)BB * TT * HH);
  float* scores = alloc((size_t)BB * TT);
  (void)ws_size; (void)in_sizes; (void)n_in; (void)out_size;

  hipLaunchKernelGGL(k_prep, dim3(256), dim3(256), 0, stream,
                     Wih0, Whh0, Wih1, Whh1, W1, fc1w,
                     Wih0T, Whh0T, Wih1T, Whh1T, W1T, fc1T);
  hipLaunchKernelGGL(k_xw0, dim3((BB * TT) / 32), dim3(512), 0, stream, texts, emb, Wih0T, bih0, xwbuf);
  hipLaunchKernelGGL(k_rec, dim3(BB), dim3(512), 0, stream, Whh0T, bhh0, xwbuf, lengths, out0);
  hipLaunchKernelGGL(k_xw1, dim3((BB * TT) / 32), dim3(512), 0, stream, out0, Wih1T, bih1, xwbuf);
  hipLaunchKernelGGL(k_rec, dim3(BB), dim3(512), 0, stream, Whh1T, bhh1, xwbuf, lengths, out1);
  hipLaunchKernelGGL(k_scores, dim3((BB * TT) / 32), dim3(256), 0, stream, out1, W1T, w2, scores);
  hipLaunchKernelGGL(k_final, dim3(BB), dim3(512), 0, stream, out1, scores, fc1T, fc1b, fc2w, fc2b, logits);
}